// Round 6
// baseline (232.535 us; speedup 1.0000x reference)
//
#include <hip/hip_runtime.h>
#include <math.h>

#define N_NODES 50000
#define IN_DIM 8
#define HID 32
#define D1 128   // HID * HEADS

// Bucket CSR record: 64 ints per node = {cnt, slot0..slot62}. Counter and
// slots share a 256-B record so fill's atomic + dependent store usually hit
// the SAME cache line, and counters are 256 B apart (no 16-counters-per-line
// atomic serialization). Max deg (Poisson(16)) << 63; store guarded anyway.
#define REC 64
#define CAPE 63

// XCD-partitioned bucket fill: 8 groups (g = blockIdx&7 -> same XCD under
// round-robin dispatch), each group owns dst range of N_NODES/8 = 6250.
#define FG 8
#define FB 128          // blocks per group
#define GRANGE (N_NODES / FG)
#define FILL_BLOCKS (FG * FB)                 // 1024
#define SD1_BLOCKS ((N_NODES + 255) / 256)    // 196

// ---------------------------------------------------------------------------
// FUSED: bucket fill (blocks 0..1023) + s1/px fold (blocks 1024..1219).
// SD1 section builds the packed layer-1 gather record:
//   px[n][0..7] = x[n], px[n][8] = s1[n]   (stride 16 floats = 64 B, aligned)
// so the aggregation gather touches ONE random line per edge instead of ~2.5.
// ---------------------------------------------------------------------------
__global__ void k_fill_sd1(const int* __restrict__ src, const int* __restrict__ dst,
                           int* __restrict__ bkt,
                           const float* __restrict__ x, const float* __restrict__ W1,
                           const float* __restrict__ a1,
                           float* __restrict__ px, float* __restrict__ d1,
                           int n_edges) {
    __shared__ float bs[IN_DIM], bd[IN_DIM];
    const int t = threadIdx.x;
    if (blockIdx.x < FILL_BLOCKS) {
        // ---- partitioned bucket fill ----
        const int g = blockIdx.x & (FG - 1);
        const int blk = blockIdx.x >> 3;
        const int lo = g * GRANGE, hi = lo + GRANGE;
        const int base = blk * blockDim.x + t;
        const int step = FB * blockDim.x;
        for (int i = base; i * 4 < n_edges; i += step) {
            const int4 d4 = *(const int4*)&dst[i * 4];
            const bool mx = d4.x >= lo && d4.x < hi;
            const bool my = d4.y >= lo && d4.y < hi;
            const bool mz = d4.z >= lo && d4.z < hi;
            const bool mw = d4.w >= lo && d4.w < hi;
            if (mx | my | mz | mw) {
                const int4 s4 = *(const int4*)&src[i * 4];
                if (mx) { const int p = atomicAdd(&bkt[d4.x * REC], 1); if (p < CAPE) bkt[d4.x * REC + 1 + p] = s4.x; }
                if (my) { const int p = atomicAdd(&bkt[d4.y * REC], 1); if (p < CAPE) bkt[d4.y * REC + 1 + p] = s4.y; }
                if (mz) { const int p = atomicAdd(&bkt[d4.z * REC], 1); if (p < CAPE) bkt[d4.z * REC + 1 + p] = s4.z; }
                if (mw) { const int p = atomicAdd(&bkt[d4.w * REC], 1); if (p < CAPE) bkt[d4.w * REC + 1 + p] = s4.w; }
            }
        }
    } else {
        // ---- px/d1: s1[n] = x[n]·(W1 a_src) packed with x; d1 dense ----
        if (t < 16) {
            const int k = t & 7;
            const float* av = a1 + ((t < 8) ? 0 : D1);
            float acc = 0.f;
            for (int j = 0; j < D1; ++j) acc += W1[k * D1 + j] * av[j];
            if (t < 8) bs[k] = acc; else bd[k] = acc;
        }
        __syncthreads();
        const int node = (blockIdx.x - FILL_BLOCKS) * blockDim.x + t;
        if (node >= N_NODES) return;
        const float4 x0 = *(const float4*)&x[node * 8];
        const float4 x1 = *(const float4*)&x[node * 8 + 4];
        const float s1v = x0.x*bs[0] + x0.y*bs[1] + x0.z*bs[2] + x0.w*bs[3]
                        + x1.x*bs[4] + x1.y*bs[5] + x1.z*bs[6] + x1.w*bs[7];
        d1[node]       = x0.x*bd[0] + x0.y*bd[1] + x0.z*bd[2] + x0.w*bd[3]
                        + x1.x*bd[4] + x1.y*bd[5] + x1.z*bd[6] + x1.w*bd[7];
        *(float4*)&px[node * 16]     = x0;
        *(float4*)&px[node * 16 + 4] = x1;
        px[node * 16 + 8] = s1v;
    }
}

// ---------------------------------------------------------------------------
// FUSED layer-1 aggregation + node-mid. 8 nodes/block (2 nodes/wave).
// Phase 1 : 1 lane/edge, 32 slots/half; gather = ONE 64-B px line per edge
//           ({x, s1} packed). deg/slots from the bucket record.
// Phase 2 : EXACT R3 code (proven): sequential-k addressing so the compiler
//           folds immediate offsets and pipelines the loads. (R4's rotated
//           runtime index serialized the loads: 46 -> 110 us. Do not repeat.)
// ---------------------------------------------------------------------------
__global__ void k_aggr_mid(const int* __restrict__ bkt,
                           const float* __restrict__ px, const float* __restrict__ d,
                           const float* __restrict__ W1, const float* __restrict__ W2,
                           const float* __restrict__ a2,
                           float* __restrict__ Wh2,
                           float* __restrict__ s2, float* __restrict__ d2) {
    __shared__ float xa_s[8][IN_DIM];   // 8 nodes x 8 dims
    __shared__ float h_s[8][D1];        // 8 nodes x 128 (4 KB)
    const int t = threadIdx.x;
    const int wv = t >> 6;
    const int lane = t & 63;
    const int half = lane >> 5, sub = lane & 31;
    const int nodeBase = blockIdx.x * 8;          // grid = 6250 blocks exact
    // ---- phase 1: aggregation (1 lane/edge, 32 slots/half) ----
    const int node = nodeBase + wv * 2 + half;
    const int rec = node * REC;
    const int deg = bkt[rec];
    const float dn = d[node];
    float4 aLo = {0.f, 0.f, 0.f, 0.f};
    float4 aHi = {0.f, 0.f, 0.f, 0.f};
    float wsum = 0.f;
    for (int idx = sub; idx < deg; idx += 32) {
        const int se = bkt[rec + 1 + idx];
        const float4 v0 = *(const float4*)&px[se * 16];
        const float4 v1 = *(const float4*)&px[se * 16 + 4];
        const float sv = px[se * 16 + 8];
        float a = sv + dn;
        a = a > 0.f ? a : 0.2f * a;
        const float ww = expf(a);
        aLo.x += ww * v0.x;  aLo.y += ww * v0.y;
        aLo.z += ww * v0.z;  aLo.w += ww * v0.w;
        aHi.x += ww * v1.x;  aHi.y += ww * v1.y;
        aHi.z += ww * v1.z;  aHi.w += ww * v1.w;
        wsum += ww;
    }
#pragma unroll
    for (int off = 1; off < 32; off <<= 1) {
        aLo.x += __shfl_xor(aLo.x, off);
        aLo.y += __shfl_xor(aLo.y, off);
        aLo.z += __shfl_xor(aLo.z, off);
        aLo.w += __shfl_xor(aLo.w, off);
        aHi.x += __shfl_xor(aHi.x, off);
        aHi.y += __shfl_xor(aHi.y, off);
        aHi.z += __shfl_xor(aHi.z, off);
        aHi.w += __shfl_xor(aHi.w, off);
        wsum  += __shfl_xor(wsum, off);
    }
    const float inv = 1.f / (wsum + 1e-9f);
    if (sub == 0) {
        float4 o; o.x = aLo.x*inv; o.y = aLo.y*inv; o.z = aLo.z*inv; o.w = aLo.w*inv;
        *(float4*)&xa_s[wv * 2 + half][0] = o;
    } else if (sub == 1) {
        float4 o; o.x = aHi.x*inv; o.y = aHi.y*inv; o.z = aHi.z*inv; o.w = aHi.w*inv;
        *(float4*)&xa_s[wv * 2 + half][4] = o;
    }
    __syncthreads();
    // ---- phase 2a: h = elu(xa @ W1), 4 k-values per thread (stride-32) ----
    const int nloc = t >> 5;            // 0..7
    const int col = t & 31;
    const float xa0 = xa_s[nloc][0], xa1 = xa_s[nloc][1];
    const float xa2 = xa_s[nloc][2], xa3 = xa_s[nloc][3];
    const float xa4 = xa_s[nloc][4], xa5 = xa_s[nloc][5];
    const float xa6 = xa_s[nloc][6], xa7 = xa_s[nloc][7];
#pragma unroll
    for (int j = 0; j < 4; ++j) {
        const int k = col + 32 * j;
        float h = xa0 * W1[0 * D1 + k] + xa1 * W1[1 * D1 + k]
                + xa2 * W1[2 * D1 + k] + xa3 * W1[3 * D1 + k]
                + xa4 * W1[4 * D1 + k] + xa5 * W1[5 * D1 + k]
                + xa6 * W1[6 * D1 + k] + xa7 * W1[7 * D1 + k];
        h_s[nloc][k] = h > 0.f ? h : (expf(h) - 1.f);   // elu
    }
    __syncthreads();
    // ---- phase 2b: output col = `col` of node nloc ----
    float o = 0.f;
#pragma unroll 8
    for (int k = 0; k < D1; ++k) o += h_s[nloc][k] * W2[k * HID + col];
    float ss = o * a2[col];
    float dd = o * a2[HID + col];
#pragma unroll
    for (int off = 1; off < 32; off <<= 1) {
        ss += __shfl_xor(ss, off);
        dd += __shfl_xor(dd, off);
    }
    const int node2 = nodeBase + nloc;
    Wh2[node2 * HID + col] = o;
    if (col == 0) { s2[node2] = ss; d2[node2] = dd; }
}

// ---------------------------------------------------------------------------
// Layer-2 aggregation + FUSED MLP HEAD, single pass, 2 nodes/wave.
// ---------------------------------------------------------------------------
__global__ void k_aggr32_head(const int* __restrict__ bkt,
                              const float* __restrict__ s, const float* __restrict__ d,
                              const float* __restrict__ Wh,
                              const float* __restrict__ hw1, const float* __restrict__ hb1,
                              const float* __restrict__ hw2, const float* __restrict__ hb2,
                              float* __restrict__ scores) {
    const int w = (blockIdx.x * blockDim.x + threadIdx.x) >> 6;
    const int lane = threadIdx.x & 63;
    const int half = lane >> 5, sub = lane & 31, base = lane & 32;
    const int node = w * 2 + half;
    if (node >= N_NODES) return;
    const int rec = node * REC;
    const int deg = bkt[rec];
    const float dn = d[node];
    const int slot = sub >> 3;       // 4 edge slots per half
    const int cp = sub & 7;          // float4 -> cols 4cp..4cp+3
    float4 acc = {0.f, 0.f, 0.f, 0.f};
    float wsum = 0.f;
    for (int idx = slot; idx < deg; idx += 4) {
        const int se = bkt[rec + 1 + idx];
        float a = s[se] + dn;
        a = a > 0.f ? a : 0.2f * a;
        const float ww = expf(a);
        const float4 v = *(const float4*)&Wh[se * HID + cp * 4];
        acc.x += ww * v.x;  acc.y += ww * v.y;
        acc.z += ww * v.z;  acc.w += ww * v.w;
        wsum += ww;
    }
#pragma unroll
    for (int off = 8; off < 32; off <<= 1) {
        acc.x += __shfl_xor(acc.x, off);
        acc.y += __shfl_xor(acc.y, off);
        acc.z += __shfl_xor(acc.z, off);
        acc.w += __shfl_xor(acc.w, off);
        wsum  += __shfl_xor(wsum, off);
    }
    const float inv = 1.f / (wsum + 1e-9f);
    acc.x *= inv;  acc.y *= inv;  acc.z *= inv;  acc.w *= inv;
    // ---- fused head (per half; lane sub = output col) ----
    const int srcl = base + (sub >> 2);
    const float g0 = __shfl(acc.x, srcl);
    const float g1 = __shfl(acc.y, srcl);
    const float g2 = __shfl(acc.z, srcl);
    const float g3 = __shfl(acc.w, srcl);
    const int r = sub & 3;
    float v = (r == 0) ? g0 : (r == 1) ? g1 : (r == 2) ? g2 : g3;
    const float h = v > 0.f ? v : (expf(v) - 1.f);   // elu
    float z = hb1[sub];
#pragma unroll
    for (int k = 0; k < HID; ++k) {
        const float hk = __shfl(h, base + k);
        z += hk * hw1[k * HID + sub];
    }
    z = 0.5f * z * (1.f + erff(z * 0.7071067811865475f));  // exact gelu
    float sc = z * hw2[sub];
#pragma unroll
    for (int off = 16; off > 0; off >>= 1) sc += __shfl_xor(sc, off);
    if (sub == 0) scores[node] = sc + hb2[0];
}

// ---------------------------------------------------------------------------
extern "C" void kernel_launch(void* const* d_in, const int* in_sizes, int n_in,
                              void* d_out, int out_size, void* d_ws, size_t ws_size,
                              hipStream_t stream) {
    const float* x   = (const float*)d_in[0];
    const int*   ei  = (const int*)d_in[1];
    const float* W1  = (const float*)d_in[2];
    const float* a1  = (const float*)d_in[3];
    const float* W2  = (const float*)d_in[4];
    const float* a2  = (const float*)d_in[5];
    const float* hw1 = (const float*)d_in[6];
    const float* hb1 = (const float*)d_in[7];
    const float* hw2 = (const float*)d_in[8];
    const float* hb2 = (const float*)d_in[9];
    float* out = (float*)d_out;

    const int n_edges = in_sizes[1] / 2;
    const int* src = ei;
    const int* dst = ei + n_edges;

    // workspace carve-up (px first: 64-B-aligned rows)
    float* p = (float*)d_ws;
    float* px   = p; p += (size_t)N_NODES * 16;        // {x[8], s1, pad} 64 B/node
    float* Wh2  = p; p += (size_t)N_NODES * HID;
    float* d1   = p; p += N_NODES;
    float* s2   = p; p += N_NODES;
    float* d2   = p; p += N_NODES;
    int* bkt    = (int*)p; p += (size_t)N_NODES * REC; // {cnt, slots[63]} 256 B/node

    hipMemsetAsync(bkt, 0, (size_t)N_NODES * REC * sizeof(int), stream);

    const int AGGR_BLOCKS = (N_NODES * 32 + 255) / 256;   // 6250

    // bucket CSR build + px/d1 (fused)
    k_fill_sd1<<<FILL_BLOCKS + SD1_BLOCKS, 256, 0, stream>>>(
        src, dst, bkt, x, W1, a1, px, d1, n_edges);

    // ----- layer 1 aggregation + node-mid fused (xa never leaves LDS) -----
    k_aggr_mid<<<(N_NODES + 7) / 8, 256, 0, stream>>>(bkt, px, d1,
                                                      W1, W2, a2, Wh2, s2, d2);

    // ----- layer 2 aggregation fused with MLP head -----
    k_aggr32_head<<<AGGR_BLOCKS, 256, 0, stream>>>(bkt, s2, d2, Wh2,
                                                   hw1, hb1, hw2, hb2, out);
}

// Round 7
// 221.779 us; speedup vs baseline: 1.0485x; 1.0485x over previous
//
#include <hip/hip_runtime.h>
#include <math.h>

#define N_NODES 50000
#define IN_DIM 8
#define HID 32
#define D1 128   // HID * HEADS

// Fixed-capacity bucket CSR: input graph is fixed (seed 0), degrees ~Poisson(16),
// max degree far below CAP=64. Store guarded anyway.
// NOTE (R6 lesson): cnt (device-scope atomics) and esrc (plain stores) MUST
// stay on separate cache lines — merging them caused L2<->memory-side thrash
// (WRITE_SIZE 6.6 -> 45 MB, fill 40 -> 90 us).
#define CAP 64

// XCD-partitioned bucket fill: 8 groups (g = blockIdx&7 -> same XCD under
// round-robin dispatch), each group owns dst range of N_NODES/8 = 6250.
#define FG 8
#define FB 128          // blocks per group
#define GRANGE (N_NODES / FG)
#define FILL_BLOCKS (FG * FB)                 // 1024
#define SD1_BLOCKS ((N_NODES + 255) / 256)    // 196

// ---------------------------------------------------------------------------
// FUSED: bucket fill (blocks 0..1023) + s1/d1 fold (blocks 1024..1219).
// EXACT R5 code (proven).
// ---------------------------------------------------------------------------
__global__ void k_fill_sd1(const int* __restrict__ src, const int* __restrict__ dst,
                           int* __restrict__ cnt, int* __restrict__ esrc,
                           const float* __restrict__ x, const float* __restrict__ W1,
                           const float* __restrict__ a1,
                           float* __restrict__ s1, float* __restrict__ d1,
                           int n_edges) {
    __shared__ float bs[IN_DIM], bd[IN_DIM];
    const int t = threadIdx.x;
    if (blockIdx.x < FILL_BLOCKS) {
        // ---- partitioned bucket fill ----
        const int g = blockIdx.x & (FG - 1);
        const int blk = blockIdx.x >> 3;
        const int lo = g * GRANGE, hi = lo + GRANGE;
        const int base = blk * blockDim.x + t;
        const int step = FB * blockDim.x;
        for (int i = base; i * 4 < n_edges; i += step) {
            const int4 d4 = *(const int4*)&dst[i * 4];
            const bool mx = d4.x >= lo && d4.x < hi;
            const bool my = d4.y >= lo && d4.y < hi;
            const bool mz = d4.z >= lo && d4.z < hi;
            const bool mw = d4.w >= lo && d4.w < hi;
            if (mx | my | mz | mw) {
                const int4 s4 = *(const int4*)&src[i * 4];
                if (mx) { const int p = atomicAdd(&cnt[d4.x], 1); if (p < CAP) esrc[d4.x * CAP + p] = s4.x; }
                if (my) { const int p = atomicAdd(&cnt[d4.y], 1); if (p < CAP) esrc[d4.y * CAP + p] = s4.y; }
                if (mz) { const int p = atomicAdd(&cnt[d4.z], 1); if (p < CAP) esrc[d4.z * CAP + p] = s4.z; }
                if (mw) { const int p = atomicAdd(&cnt[d4.w], 1); if (p < CAP) esrc[d4.w * CAP + p] = s4.w; }
            }
        }
    } else {
        // ---- s1/d1: s1[n] = x[n]·(W1 a_src), d1[n] = x[n]·(W1 a_dst) ----
        if (t < 16) {
            const int k = t & 7;
            const float* av = a1 + ((t < 8) ? 0 : D1);
            float acc = 0.f;
            for (int j = 0; j < D1; ++j) acc += W1[k * D1 + j] * av[j];
            if (t < 8) bs[k] = acc; else bd[k] = acc;
        }
        __syncthreads();
        const int node = (blockIdx.x - FILL_BLOCKS) * blockDim.x + t;
        if (node >= N_NODES) return;
        const float4 x0 = *(const float4*)&x[node * 8];
        const float4 x1 = *(const float4*)&x[node * 8 + 4];
        s1[node] = x0.x*bs[0] + x0.y*bs[1] + x0.z*bs[2] + x0.w*bs[3]
                 + x1.x*bs[4] + x1.y*bs[5] + x1.z*bs[6] + x1.w*bs[7];
        d1[node] = x0.x*bd[0] + x0.y*bd[1] + x0.z*bd[2] + x0.w*bd[3]
                 + x1.x*bd[4] + x1.y*bd[5] + x1.z*bd[6] + x1.w*bd[7];
    }
}

// ---------------------------------------------------------------------------
// FUSED layer-1 aggregation + node-mid. EXACT R5 code (proven 46.7 us).
// ---------------------------------------------------------------------------
__global__ void k_aggr_mid(const int* __restrict__ esrc, const int* __restrict__ cnt,
                           const float* __restrict__ s, const float* __restrict__ d,
                           const float* __restrict__ x,
                           const float* __restrict__ W1, const float* __restrict__ W2,
                           const float* __restrict__ a2,
                           float* __restrict__ Wh2,
                           float* __restrict__ s2, float* __restrict__ d2) {
    __shared__ float xa_s[8][IN_DIM];   // 8 nodes x 8 dims
    __shared__ float h_s[8][D1];        // 8 nodes x 128 (4 KB)
    const int t = threadIdx.x;
    const int wv = t >> 6;
    const int lane = t & 63;
    const int half = lane >> 5, sub = lane & 31;
    const int nodeBase = blockIdx.x * 8;          // grid = 6250 blocks exact
    // ---- phase 1: aggregation (1 lane/edge, 32 slots/half) ----
    const int node = nodeBase + wv * 2 + half;
    const int start = node * CAP;
    const int deg = cnt[node];
    const float dn = d[node];
    float4 aLo = {0.f, 0.f, 0.f, 0.f};
    float4 aHi = {0.f, 0.f, 0.f, 0.f};
    float wsum = 0.f;
    for (int idx = sub; idx < deg; idx += 32) {
        const int se = esrc[start + idx];
        float a = s[se] + dn;
        a = a > 0.f ? a : 0.2f * a;
        const float ww = expf(a);
        const float4 v0 = *(const float4*)&x[se * IN_DIM];
        const float4 v1 = *(const float4*)&x[se * IN_DIM + 4];
        aLo.x += ww * v0.x;  aLo.y += ww * v0.y;
        aLo.z += ww * v0.z;  aLo.w += ww * v0.w;
        aHi.x += ww * v1.x;  aHi.y += ww * v1.y;
        aHi.z += ww * v1.z;  aHi.w += ww * v1.w;
        wsum += ww;
    }
#pragma unroll
    for (int off = 1; off < 32; off <<= 1) {
        aLo.x += __shfl_xor(aLo.x, off);
        aLo.y += __shfl_xor(aLo.y, off);
        aLo.z += __shfl_xor(aLo.z, off);
        aLo.w += __shfl_xor(aLo.w, off);
        aHi.x += __shfl_xor(aHi.x, off);
        aHi.y += __shfl_xor(aHi.y, off);
        aHi.z += __shfl_xor(aHi.z, off);
        aHi.w += __shfl_xor(aHi.w, off);
        wsum  += __shfl_xor(wsum, off);
    }
    const float inv = 1.f / (wsum + 1e-9f);
    if (sub == 0) {
        float4 o; o.x = aLo.x*inv; o.y = aLo.y*inv; o.z = aLo.z*inv; o.w = aLo.w*inv;
        *(float4*)&xa_s[wv * 2 + half][0] = o;
    } else if (sub == 1) {
        float4 o; o.x = aHi.x*inv; o.y = aHi.y*inv; o.z = aHi.z*inv; o.w = aHi.w*inv;
        *(float4*)&xa_s[wv * 2 + half][4] = o;
    }
    __syncthreads();
    // ---- phase 2a: h = elu(xa @ W1), 4 k-values per thread (stride-32) ----
    const int nloc = t >> 5;            // 0..7
    const int col = t & 31;
    const float xa0 = xa_s[nloc][0], xa1 = xa_s[nloc][1];
    const float xa2 = xa_s[nloc][2], xa3 = xa_s[nloc][3];
    const float xa4 = xa_s[nloc][4], xa5 = xa_s[nloc][5];
    const float xa6 = xa_s[nloc][6], xa7 = xa_s[nloc][7];
#pragma unroll
    for (int j = 0; j < 4; ++j) {
        const int k = col + 32 * j;
        float h = xa0 * W1[0 * D1 + k] + xa1 * W1[1 * D1 + k]
                + xa2 * W1[2 * D1 + k] + xa3 * W1[3 * D1 + k]
                + xa4 * W1[4 * D1 + k] + xa5 * W1[5 * D1 + k]
                + xa6 * W1[6 * D1 + k] + xa7 * W1[7 * D1 + k];
        h_s[nloc][k] = h > 0.f ? h : (expf(h) - 1.f);   // elu
    }
    __syncthreads();
    // ---- phase 2b: output col = `col` of node nloc ----
    float o = 0.f;
#pragma unroll 8
    for (int k = 0; k < D1; ++k) o += h_s[nloc][k] * W2[k * HID + col];
    float ss = o * a2[col];
    float dd = o * a2[HID + col];
#pragma unroll
    for (int off = 1; off < 32; off <<= 1) {
        ss += __shfl_xor(ss, off);
        dd += __shfl_xor(dd, off);
    }
    const int node2 = nodeBase + nloc;
    Wh2[node2 * HID + col] = o;
    if (col == 0) { s2[node2] = ss; d2[node2] = dd; }
}

// ---------------------------------------------------------------------------
// Layer-2 aggregation + FUSED MLP HEAD — RESTRUCTURED: 1 node/wave.
// 32 edge slots x 2 col-halves: lane (slot=lane>>1, ch=lane&1) reads ONE
// 64-B line of Wh[se] (cols ch*16..+15). deg<=32 gathers in ONE round
// (4 serial rounds before); 2 random lines/edge -> 1.
// Reduce 17 values over slot-stride lanes (off 2..32); h cols 0-15 live in
// even lanes, 16-31 in odd; MLP redistributes via compile-time __shfl.
// ---------------------------------------------------------------------------
__global__ void k_aggr32_head(const int* __restrict__ esrc, const int* __restrict__ cnt,
                              const float* __restrict__ s, const float* __restrict__ d,
                              const float* __restrict__ Wh,
                              const float* __restrict__ hw1, const float* __restrict__ hb1,
                              const float* __restrict__ hw2, const float* __restrict__ hb2,
                              float* __restrict__ scores) {
    const int node = (blockIdx.x * blockDim.x + threadIdx.x) >> 6;   // 1 wave = 1 node
    const int lane = threadIdx.x & 63;
    if (node >= N_NODES) return;
    const int start = node * CAP;
    const int deg = cnt[node];
    const float dn = d[node];
    const int slot = lane >> 1;        // 32 edge slots
    const int ch = lane & 1;           // col half: cols ch*16 .. ch*16+15
    float acc[16];
#pragma unroll
    for (int j = 0; j < 16; ++j) acc[j] = 0.f;
    float wsum = 0.f;
    for (int base = 0; base < deg; base += 32) {   // 1 round for deg<=32 (typ.)
        const int idx = base + slot;
        if (idx < deg) {
            const int se = esrc[start + idx];
            float a = s[se] + dn;
            a = a > 0.f ? a : 0.2f * a;
            const float ww = expf(a);
            const float* wp = &Wh[se * HID + ch * 16];   // one 64-B line
            const float4 v0 = *(const float4*)&wp[0];
            const float4 v1 = *(const float4*)&wp[4];
            const float4 v2 = *(const float4*)&wp[8];
            const float4 v3 = *(const float4*)&wp[12];
            acc[0]  += ww*v0.x; acc[1]  += ww*v0.y; acc[2]  += ww*v0.z; acc[3]  += ww*v0.w;
            acc[4]  += ww*v1.x; acc[5]  += ww*v1.y; acc[6]  += ww*v1.z; acc[7]  += ww*v1.w;
            acc[8]  += ww*v2.x; acc[9]  += ww*v2.y; acc[10] += ww*v2.z; acc[11] += ww*v2.w;
            acc[12] += ww*v3.x; acc[13] += ww*v3.y; acc[14] += ww*v3.z; acc[15] += ww*v3.w;
            wsum += ww;
        }
    }
    // reduce over slots (lane stride 2; parity groups stay separate)
#pragma unroll
    for (int off = 2; off < 64; off <<= 1) {
#pragma unroll
        for (int j = 0; j < 16; ++j) acc[j] += __shfl_xor(acc[j], off);
        wsum += __shfl_xor(wsum, off);
    }
    const float inv = 1.f / (wsum + 1e-9f);
    // h = elu(acc*inv); even lanes hold cols 0-15, odd lanes cols 16-31
    float h[16];
#pragma unroll
    for (int j = 0; j < 16; ++j) {
        const float v = acc[j] * inv;
        h[j] = v > 0.f ? v : (expf(v) - 1.f);
    }
    // MLP: z[c] for c = lane&31 (lanes 32-63 duplicate; harmless)
    const int c = lane & 31;
    float z = hb1[c];
#pragma unroll
    for (int k = 0; k < HID; ++k) {
        const float hk = __shfl(h[k & 15], k >> 4);   // col k lives in lane (k>>4)
        z += hk * hw1[k * HID + c];
    }
    z = 0.5f * z * (1.f + erff(z * 0.7071067811865475f));  // exact gelu
    float sc = z * hw2[c];
#pragma unroll
    for (int off = 1; off < 32; off <<= 1) sc += __shfl_xor(sc, off);
    if (lane == 0) scores[node] = sc + hb2[0];
}

// ---------------------------------------------------------------------------
extern "C" void kernel_launch(void* const* d_in, const int* in_sizes, int n_in,
                              void* d_out, int out_size, void* d_ws, size_t ws_size,
                              hipStream_t stream) {
    const float* x   = (const float*)d_in[0];
    const int*   ei  = (const int*)d_in[1];
    const float* W1  = (const float*)d_in[2];
    const float* a1  = (const float*)d_in[3];
    const float* W2  = (const float*)d_in[4];
    const float* a2  = (const float*)d_in[5];
    const float* hw1 = (const float*)d_in[6];
    const float* hb1 = (const float*)d_in[7];
    const float* hw2 = (const float*)d_in[8];
    const float* hb2 = (const float*)d_in[9];
    float* out = (float*)d_out;

    const int n_edges = in_sizes[1] / 2;
    const int* src = ei;
    const int* dst = ei + n_edges;

    // workspace carve-up (R5 layout: atomics on dense cnt, stores on esrc)
    float* p = (float*)d_ws;
    float* Wh2  = p; p += (size_t)N_NODES * HID;
    float* s1   = p; p += N_NODES;
    float* d1   = p; p += N_NODES;
    float* s2   = p; p += N_NODES;
    float* d2   = p; p += N_NODES;
    int* cnt    = (int*)p; p += N_NODES;               // per-node degree counts
    int* esrc   = (int*)p; p += (size_t)N_NODES * CAP; // bucket CSR (12.8 MB)

    hipMemsetAsync(cnt, 0, N_NODES * sizeof(int), stream);

    // bucket CSR build + s1/d1 (fused)
    k_fill_sd1<<<FILL_BLOCKS + SD1_BLOCKS, 256, 0, stream>>>(
        src, dst, cnt, esrc, x, W1, a1, s1, d1, n_edges);

    // ----- layer 1 aggregation + node-mid fused (xa never leaves LDS) -----
    k_aggr_mid<<<(N_NODES + 7) / 8, 256, 0, stream>>>(esrc, cnt, s1, d1, x,
                                                      W1, W2, a2, Wh2, s2, d2);

    // ----- layer 2 aggregation fused with MLP head (1 node/wave) -----
    k_aggr32_head<<<(N_NODES * 64 + 255) / 256, 256, 0, stream>>>(
        esrc, cnt, s2, d2, Wh2, hw1, hb1, hw2, hb2, out);
}

// Round 8
// 180.897 us; speedup vs baseline: 1.2855x; 1.2260x over previous
//
#include <hip/hip_runtime.h>
#include <math.h>

#define N_NODES 50000
#define IN_DIM 8
#define HID 32
#define D1 128   // HID * HEADS

// Fixed-capacity bucket CSR: input graph is fixed (seed 0), degrees ~Poisson(16),
// max degree far below CAP=64. Store guarded anyway.
// R6 lesson: cnt (device-scope atomics) and esrc (plain stores) MUST stay on
// separate cache lines — merging them caused WRITE_SIZE 6.6->45 MB, fill 40->90us.
// R7 lesson: do not trade gather lines for cross-lane shuffles — shuffle VALU
// cost exceeded the line saving (head 43->74.5us).
#define CAP 64

// XCD-partitioned bucket fill: 8 groups (g = blockIdx&7 -> same XCD under
// round-robin dispatch), each group owns dst range of N_NODES/8 = 6250.
#define FG 8
#define FB 128          // blocks per group
#define GRANGE (N_NODES / FG)
#define FILL_BLOCKS (FG * FB)                 // 1024
#define SD1_BLOCKS ((N_NODES + 255) / 256)    // 196

// ---------------------------------------------------------------------------
// FUSED: bucket fill (blocks 0..1023, EXACT R5) + px/d1 fold.
// px[n] = {x[n][0..7], s1[n], 7 pad} — one 64-B record so the layer-1 gather
// touches ONE random line per edge instead of two (s1 line + x line).
// ---------------------------------------------------------------------------
__global__ void k_fill_sd1(const int* __restrict__ src, const int* __restrict__ dst,
                           int* __restrict__ cnt, int* __restrict__ esrc,
                           const float* __restrict__ x, const float* __restrict__ W1,
                           const float* __restrict__ a1,
                           float* __restrict__ px, float* __restrict__ d1,
                           int n_edges) {
    __shared__ float bs[IN_DIM], bd[IN_DIM];
    const int t = threadIdx.x;
    if (blockIdx.x < FILL_BLOCKS) {
        // ---- partitioned bucket fill (EXACT R5) ----
        const int g = blockIdx.x & (FG - 1);
        const int blk = blockIdx.x >> 3;
        const int lo = g * GRANGE, hi = lo + GRANGE;
        const int base = blk * blockDim.x + t;
        const int step = FB * blockDim.x;
        for (int i = base; i * 4 < n_edges; i += step) {
            const int4 d4 = *(const int4*)&dst[i * 4];
            const bool mx = d4.x >= lo && d4.x < hi;
            const bool my = d4.y >= lo && d4.y < hi;
            const bool mz = d4.z >= lo && d4.z < hi;
            const bool mw = d4.w >= lo && d4.w < hi;
            if (mx | my | mz | mw) {
                const int4 s4 = *(const int4*)&src[i * 4];
                if (mx) { const int p = atomicAdd(&cnt[d4.x], 1); if (p < CAP) esrc[d4.x * CAP + p] = s4.x; }
                if (my) { const int p = atomicAdd(&cnt[d4.y], 1); if (p < CAP) esrc[d4.y * CAP + p] = s4.y; }
                if (mz) { const int p = atomicAdd(&cnt[d4.z], 1); if (p < CAP) esrc[d4.z * CAP + p] = s4.z; }
                if (mw) { const int p = atomicAdd(&cnt[d4.w], 1); if (p < CAP) esrc[d4.w * CAP + p] = s4.w; }
            }
        }
    } else {
        // ---- px/d1: s1[n] = x[n]·(W1 a_src) packed with x; d1 dense ----
        if (t < 16) {
            const int k = t & 7;
            const float* av = a1 + ((t < 8) ? 0 : D1);
            float acc = 0.f;
            for (int j = 0; j < D1; ++j) acc += W1[k * D1 + j] * av[j];
            if (t < 8) bs[k] = acc; else bd[k] = acc;
        }
        __syncthreads();
        const int node = (blockIdx.x - FILL_BLOCKS) * blockDim.x + t;
        if (node >= N_NODES) return;
        const float4 x0 = *(const float4*)&x[node * 8];
        const float4 x1 = *(const float4*)&x[node * 8 + 4];
        const float s1v = x0.x*bs[0] + x0.y*bs[1] + x0.z*bs[2] + x0.w*bs[3]
                        + x1.x*bs[4] + x1.y*bs[5] + x1.z*bs[6] + x1.w*bs[7];
        d1[node]       = x0.x*bd[0] + x0.y*bd[1] + x0.z*bd[2] + x0.w*bd[3]
                        + x1.x*bd[4] + x1.y*bd[5] + x1.z*bd[6] + x1.w*bd[7];
        *(float4*)&px[node * 16]     = x0;
        *(float4*)&px[node * 16 + 4] = x1;
        px[node * 16 + 8] = s1v;
    }
}

// ---------------------------------------------------------------------------
// FUSED layer-1 aggregation + node-mid. 8 nodes/block (2 nodes/wave).
// Phase 1 : R5 structure, but gather reads the packed px record — ONE 64-B
//           random line per edge ({x, s1} together).
// Phase 2 : EXACT R3/R5 code (proven): sequential-k addressing so the
//           compiler folds immediate offsets and pipelines the loads.
// ---------------------------------------------------------------------------
__global__ void k_aggr_mid(const int* __restrict__ esrc, const int* __restrict__ cnt,
                           const float* __restrict__ px, const float* __restrict__ d,
                           const float* __restrict__ W1, const float* __restrict__ W2,
                           const float* __restrict__ a2,
                           float* __restrict__ Wh2,
                           float* __restrict__ s2, float* __restrict__ d2) {
    __shared__ float xa_s[8][IN_DIM];   // 8 nodes x 8 dims
    __shared__ float h_s[8][D1];        // 8 nodes x 128 (4 KB)
    const int t = threadIdx.x;
    const int wv = t >> 6;
    const int lane = t & 63;
    const int half = lane >> 5, sub = lane & 31;
    const int nodeBase = blockIdx.x * 8;          // grid = 6250 blocks exact
    // ---- phase 1: aggregation (1 lane/edge, 32 slots/half) ----
    const int node = nodeBase + wv * 2 + half;
    const int start = node * CAP;
    const int deg = cnt[node];
    const float dn = d[node];
    float4 aLo = {0.f, 0.f, 0.f, 0.f};
    float4 aHi = {0.f, 0.f, 0.f, 0.f};
    float wsum = 0.f;
    for (int idx = sub; idx < deg; idx += 32) {
        const int se = esrc[start + idx];
        const float4 v0 = *(const float4*)&px[se * 16];
        const float4 v1 = *(const float4*)&px[se * 16 + 4];
        const float sv = px[se * 16 + 8];
        float a = sv + dn;
        a = a > 0.f ? a : 0.2f * a;
        const float ww = expf(a);
        aLo.x += ww * v0.x;  aLo.y += ww * v0.y;
        aLo.z += ww * v0.z;  aLo.w += ww * v0.w;
        aHi.x += ww * v1.x;  aHi.y += ww * v1.y;
        aHi.z += ww * v1.z;  aHi.w += ww * v1.w;
        wsum += ww;
    }
#pragma unroll
    for (int off = 1; off < 32; off <<= 1) {
        aLo.x += __shfl_xor(aLo.x, off);
        aLo.y += __shfl_xor(aLo.y, off);
        aLo.z += __shfl_xor(aLo.z, off);
        aLo.w += __shfl_xor(aLo.w, off);
        aHi.x += __shfl_xor(aHi.x, off);
        aHi.y += __shfl_xor(aHi.y, off);
        aHi.z += __shfl_xor(aHi.z, off);
        aHi.w += __shfl_xor(aHi.w, off);
        wsum  += __shfl_xor(wsum, off);
    }
    const float inv = 1.f / (wsum + 1e-9f);
    if (sub == 0) {
        float4 o; o.x = aLo.x*inv; o.y = aLo.y*inv; o.z = aLo.z*inv; o.w = aLo.w*inv;
        *(float4*)&xa_s[wv * 2 + half][0] = o;
    } else if (sub == 1) {
        float4 o; o.x = aHi.x*inv; o.y = aHi.y*inv; o.z = aHi.z*inv; o.w = aHi.w*inv;
        *(float4*)&xa_s[wv * 2 + half][4] = o;
    }
    __syncthreads();
    // ---- phase 2a: h = elu(xa @ W1), 4 k-values per thread (stride-32) ----
    const int nloc = t >> 5;            // 0..7
    const int col = t & 31;
    const float xa0 = xa_s[nloc][0], xa1 = xa_s[nloc][1];
    const float xa2 = xa_s[nloc][2], xa3 = xa_s[nloc][3];
    const float xa4 = xa_s[nloc][4], xa5 = xa_s[nloc][5];
    const float xa6 = xa_s[nloc][6], xa7 = xa_s[nloc][7];
#pragma unroll
    for (int j = 0; j < 4; ++j) {
        const int k = col + 32 * j;
        float h = xa0 * W1[0 * D1 + k] + xa1 * W1[1 * D1 + k]
                + xa2 * W1[2 * D1 + k] + xa3 * W1[3 * D1 + k]
                + xa4 * W1[4 * D1 + k] + xa5 * W1[5 * D1 + k]
                + xa6 * W1[6 * D1 + k] + xa7 * W1[7 * D1 + k];
        h_s[nloc][k] = h > 0.f ? h : (expf(h) - 1.f);   // elu
    }
    __syncthreads();
    // ---- phase 2b: output col = `col` of node nloc ----
    float o = 0.f;
#pragma unroll 8
    for (int k = 0; k < D1; ++k) o += h_s[nloc][k] * W2[k * HID + col];
    float ss = o * a2[col];
    float dd = o * a2[HID + col];
#pragma unroll
    for (int off = 1; off < 32; off <<= 1) {
        ss += __shfl_xor(ss, off);
        dd += __shfl_xor(dd, off);
    }
    const int node2 = nodeBase + nloc;
    Wh2[node2 * HID + col] = o;
    if (col == 0) { s2[node2] = ss; d2[node2] = dd; }
}

// ---------------------------------------------------------------------------
// Layer-2 aggregation + FUSED MLP HEAD, single pass, 2 nodes/wave.
// EXACT R2-R5 code (proven ~43 us; at its 3-random-lines/edge floor).
// ---------------------------------------------------------------------------
__global__ void k_aggr32_head(const int* __restrict__ esrc, const int* __restrict__ cnt,
                              const float* __restrict__ s, const float* __restrict__ d,
                              const float* __restrict__ Wh,
                              const float* __restrict__ hw1, const float* __restrict__ hb1,
                              const float* __restrict__ hw2, const float* __restrict__ hb2,
                              float* __restrict__ scores) {
    const int w = (blockIdx.x * blockDim.x + threadIdx.x) >> 6;
    const int lane = threadIdx.x & 63;
    const int half = lane >> 5, sub = lane & 31, base = lane & 32;
    const int node = w * 2 + half;
    if (node >= N_NODES) return;
    const int start = node * CAP;
    const int deg = cnt[node];
    const float dn = d[node];
    const int slot = sub >> 3;       // 4 edge slots per half
    const int cp = sub & 7;          // float4 -> cols 4cp..4cp+3
    float4 acc = {0.f, 0.f, 0.f, 0.f};
    float wsum = 0.f;
    for (int idx = slot; idx < deg; idx += 4) {
        const int se = esrc[start + idx];
        float a = s[se] + dn;
        a = a > 0.f ? a : 0.2f * a;
        const float ww = expf(a);
        const float4 v = *(const float4*)&Wh[se * HID + cp * 4];
        acc.x += ww * v.x;  acc.y += ww * v.y;
        acc.z += ww * v.z;  acc.w += ww * v.w;
        wsum += ww;
    }
#pragma unroll
    for (int off = 8; off < 32; off <<= 1) {
        acc.x += __shfl_xor(acc.x, off);
        acc.y += __shfl_xor(acc.y, off);
        acc.z += __shfl_xor(acc.z, off);
        acc.w += __shfl_xor(acc.w, off);
        wsum  += __shfl_xor(wsum, off);
    }
    const float inv = 1.f / (wsum + 1e-9f);
    acc.x *= inv;  acc.y *= inv;  acc.z *= inv;  acc.w *= inv;
    // ---- fused head (per half; lane sub = output col) ----
    const int srcl = base + (sub >> 2);
    const float g0 = __shfl(acc.x, srcl);
    const float g1 = __shfl(acc.y, srcl);
    const float g2 = __shfl(acc.z, srcl);
    const float g3 = __shfl(acc.w, srcl);
    const int r = sub & 3;
    float v = (r == 0) ? g0 : (r == 1) ? g1 : (r == 2) ? g2 : g3;
    const float h = v > 0.f ? v : (expf(v) - 1.f);   // elu
    float z = hb1[sub];
#pragma unroll
    for (int k = 0; k < HID; ++k) {
        const float hk = __shfl(h, base + k);
        z += hk * hw1[k * HID + sub];
    }
    z = 0.5f * z * (1.f + erff(z * 0.7071067811865475f));  // exact gelu
    float sc = z * hw2[sub];
#pragma unroll
    for (int off = 16; off > 0; off >>= 1) sc += __shfl_xor(sc, off);
    if (sub == 0) scores[node] = sc + hb2[0];
}

// ---------------------------------------------------------------------------
extern "C" void kernel_launch(void* const* d_in, const int* in_sizes, int n_in,
                              void* d_out, int out_size, void* d_ws, size_t ws_size,
                              hipStream_t stream) {
    const float* x   = (const float*)d_in[0];
    const int*   ei  = (const int*)d_in[1];
    const float* W1  = (const float*)d_in[2];
    const float* a1  = (const float*)d_in[3];
    const float* W2  = (const float*)d_in[4];
    const float* a2  = (const float*)d_in[5];
    const float* hw1 = (const float*)d_in[6];
    const float* hb1 = (const float*)d_in[7];
    const float* hw2 = (const float*)d_in[8];
    const float* hb2 = (const float*)d_in[9];
    float* out = (float*)d_out;

    const int n_edges = in_sizes[1] / 2;
    const int* src = ei;
    const int* dst = ei + n_edges;

    // workspace carve-up (px first: 64-B-aligned rows; cnt/esrc separate — R6 lesson)
    float* p = (float*)d_ws;
    float* px   = p; p += (size_t)N_NODES * 16;        // {x[8], s1, pad} 64 B/node
    float* Wh2  = p; p += (size_t)N_NODES * HID;
    float* d1   = p; p += N_NODES;
    float* s2   = p; p += N_NODES;
    float* d2   = p; p += N_NODES;
    int* cnt    = (int*)p; p += N_NODES;               // per-node degree counts
    int* esrc   = (int*)p; p += (size_t)N_NODES * CAP; // bucket CSR (12.8 MB)

    hipMemsetAsync(cnt, 0, N_NODES * sizeof(int), stream);

    const int AGGR_BLOCKS = (N_NODES * 32 + 255) / 256;   // 6250

    // bucket CSR build + px/d1 (fused)
    k_fill_sd1<<<FILL_BLOCKS + SD1_BLOCKS, 256, 0, stream>>>(
        src, dst, cnt, esrc, x, W1, a1, px, d1, n_edges);

    // ----- layer 1 aggregation + node-mid fused (xa never leaves LDS) -----
    k_aggr_mid<<<(N_NODES + 7) / 8, 256, 0, stream>>>(esrc, cnt, px, d1,
                                                      W1, W2, a2, Wh2, s2, d2);

    // ----- layer 2 aggregation fused with MLP head (2 nodes/wave, proven) -----
    k_aggr32_head<<<AGGR_BLOCKS, 256, 0, stream>>>(esrc, cnt, s2, d2, Wh2,
                                                   hw1, hb1, hw2, hb2, out);
}